// Round 1
// baseline (635.523 us; speedup 1.0000x reference)
//
#include <hip/hip_runtime.h>
#include <hip/hip_bf16.h>

#define D_MODEL 512
#define D_FF    2048
#define NE      8
#define T_TOK   8192

typedef __attribute__((ext_vector_type(8))) short bf16x8;
typedef __attribute__((ext_vector_type(4))) float f32x4;

static __device__ __forceinline__ unsigned short f2bf(float f){
    union { float f; unsigned u; } v; v.f = f;
    unsigned r = v.u + 0x7FFFu + ((v.u >> 16) & 1u);   // RNE
    return (unsigned short)(r >> 16);
}

// ---------------- f32 -> bf16 conversion (memory-bound) ----------------
__global__ __launch_bounds__(256) void cvt_f32_bf16(const float* __restrict__ src,
                                                    unsigned short* __restrict__ dst,
                                                    int n4){
    int i = blockIdx.x * blockDim.x + threadIdx.x;
    int stride = gridDim.x * blockDim.x;
    for (; i < n4; i += stride){
        float4 v = ((const float4*)src)[i];
        ushort4 o;
        o.x = f2bf(v.x); o.y = f2bf(v.y); o.z = f2bf(v.z); o.w = f2bf(v.w);
        ((ushort4*)dst)[i] = o;
    }
}

// ---------------- router: f32 logits -> softmax -> top2 -> scatter ----------------
__global__ __launch_bounds__(256) void router_kernel(const float* __restrict__ x,
                                                     const float* __restrict__ Wr,
                                                     float* __restrict__ pair_prob,
                                                     int* __restrict__ lists,
                                                     int* __restrict__ cnt){
    int gid  = blockIdx.x * blockDim.x + threadIdx.x;
    int t    = gid >> 6;              // one wave (64 lanes) per token
    int lane = threadIdx.x & 63;
    if (t >= T_TOK) return;
    const float* xr = x + (size_t)t * D_MODEL;
    float xv[8];
    #pragma unroll
    for (int c = 0; c < 8; ++c) xv[c] = xr[lane + 64*c];
    float lg[NE];
    #pragma unroll
    for (int e = 0; e < NE; ++e){
        const float* wr = Wr + (size_t)e * D_MODEL;
        float s = 0.f;
        #pragma unroll
        for (int c = 0; c < 8; ++c) s = fmaf(xv[c], wr[lane + 64*c], s);
        #pragma unroll
        for (int off = 32; off; off >>= 1) s += __shfl_xor(s, off);
        lg[e] = s;
    }
    if (lane == 0){
        float m = lg[0];
        #pragma unroll
        for (int e = 1; e < NE; ++e) m = fmaxf(m, lg[e]);
        float sum = 0.f;
        #pragma unroll
        for (int e = 0; e < NE; ++e) sum += expf(lg[e] - m);
        // top-1 (lowest index on ties, matching lax.top_k)
        int i0 = 0; float v0 = lg[0];
        #pragma unroll
        for (int e = 1; e < NE; ++e) if (lg[e] > v0){ v0 = lg[e]; i0 = e; }
        // top-2
        int i1 = -1; float v1 = -1e30f;
        #pragma unroll
        for (int e = 0; e < NE; ++e) if (e != i0 && lg[e] > v1){ v1 = lg[e]; i1 = e; }
        float inv = 1.f / sum;
        pair_prob[2*t]   = expf(v0 - m) * inv;
        pair_prob[2*t+1] = expf(v1 - m) * inv;
        int pos0 = atomicAdd(&cnt[i0], 1);
        lists[i0 * T_TOK + pos0] = 2*t;
        int pos1 = atomicAdd(&cnt[i1], 1);
        lists[i1 * T_TOK + pos1] = 2*t + 1;
    }
}

// ---------------- fused expert FFN: GEMM1 -> GELU -> GEMM2 -> weighted atomicAdd ----------------
// block = 256 threads (4 waves), tile = 32 pairs of one expert, Y acc 32x512 in regs
__global__ __launch_bounds__(256) void moe_ffn_kernel(const unsigned short* __restrict__ x_bf,
                                                      const unsigned short* __restrict__ W1bf,
                                                      const unsigned short* __restrict__ W2bf,
                                                      const float* __restrict__ pair_prob,
                                                      const int* __restrict__ lists,
                                                      const int* __restrict__ cnt,
                                                      float* __restrict__ out){
    __shared__ __align__(16) unsigned char lds_x[32 * 1024]; // 32 rows x 512 bf16, swizzled
    __shared__ __align__(16) unsigned char lds_h[32 * 128];  // 32 rows x 64 bf16, swizzled
    __shared__ int   s_tok[32];
    __shared__ float s_prob[32];

    // decode (expert, tile) from flat blockIdx via per-expert tile counts
    int e = -1, tile = 0, rem = blockIdx.x;
    #pragma unroll
    for (int i = 0; i < NE; ++i){
        int ti = (cnt[i] + 31) >> 5;
        if (e < 0){
            if (rem < ti){ e = i; tile = rem; } else rem -= ti;
        }
    }
    if (e < 0) return;
    int ne = cnt[e];
    int nrows = ne - tile * 32; if (nrows > 32) nrows = 32;

    int tid = threadIdx.x;
    if (tid < 32){
        int idx = tile * 32 + tid;
        int valid = idx < ne;
        int pair = valid ? lists[e * T_TOK + idx] : 0;
        s_tok[tid]  = valid ? (pair >> 1) : 0;
        s_prob[tid] = valid ? pair_prob[pair] : 0.f;
    }
    __syncthreads();

    // stage gathered X rows (bf16) into swizzled LDS
    {
        int row  = tid >> 3;
        int cseg = (tid & 7) * 64;
        const unsigned short* src = x_bf + (size_t)s_tok[row] * D_MODEL + cseg;
        int sw = (row & 7) << 4;
        #pragma unroll
        for (int g = 0; g < 8; ++g){
            int4 v = *(const int4*)(src + g * 8);
            int col2 = (cseg + g * 8) * 2;
            *(int4*)(lds_x + row * 1024 + (col2 ^ sw)) = v;
        }
    }
    __syncthreads();

    int wv   = tid >> 6;
    int lane = tid & 63;
    int l15  = lane & 15;
    int lk   = lane >> 4;

    f32x4 zero4 = {0.f, 0.f, 0.f, 0.f};
    f32x4 yacc[2][8];
    #pragma unroll
    for (int i = 0; i < 2; ++i)
        #pragma unroll
        for (int j = 0; j < 8; ++j) yacc[i][j] = zero4;

    const unsigned short* w1r = W1bf + (size_t)e * D_FF * D_MODEL;
    const unsigned short* w2r = W2bf + (size_t)e * D_MODEL * D_FF;

    int ar0 = l15, ar1 = 16 + l15;
    int swz = (l15 & 7) << 4;   // (ar0&7)<<4 == (ar1&7)<<4

    for (int fc = 0; fc < 32; ++fc){
        int f0 = fc * 64;
        // ---- GEMM1: Hc[32][16] for this wave's f-slab, K = 512
        f32x4 hacc0 = zero4, hacc1 = zero4;
        const unsigned short* w1p = w1r + (size_t)(f0 + wv * 16 + l15) * D_MODEL + lk * 8;
        #pragma unroll
        for (int ks = 0; ks < 16; ++ks){
            int col2 = (ks * 32 + lk * 8) * 2;
            bf16x8 a0 = *(const bf16x8*)(lds_x + ar0 * 1024 + (col2 ^ swz));
            bf16x8 a1 = *(const bf16x8*)(lds_x + ar1 * 1024 + (col2 ^ swz));
            bf16x8 bb = *(const bf16x8*)(w1p + ks * 32);
            hacc0 = __builtin_amdgcn_mfma_f32_16x16x32_bf16(a0, bb, hacc0, 0, 0, 0);
            hacc1 = __builtin_amdgcn_mfma_f32_16x16x32_bf16(a1, bb, hacc1, 0, 0, 0);
        }
        __syncthreads();   // previous GEMM2 done reading lds_h
        // ---- exact-erf GELU, restage h as bf16 (swizzled). C/D map: col=lane&15, row=(lane>>4)*4+reg
        {
            int fl2 = (wv * 16 + l15) * 2;
            #pragma unroll
            for (int r = 0; r < 4; ++r){
                int t0 = lk * 4 + r;
                float g0 = hacc0[r];
                g0 = 0.5f * g0 * (1.f + erff(g0 * 0.70710678118654752f));
                *(unsigned short*)(lds_h + t0 * 128 + (fl2 ^ ((t0 & 7) << 4))) = f2bf(g0);
                int t1 = 16 + lk * 4 + r;
                float g1 = hacc1[r];
                g1 = 0.5f * g1 * (1.f + erff(g1 * 0.70710678118654752f));
                *(unsigned short*)(lds_h + t1 * 128 + (fl2 ^ ((t1 & 7) << 4))) = f2bf(g1);
            }
        }
        __syncthreads();
        // ---- GEMM2: Yacc[32][512] += Hc(32x64) * W2[:, f-chunk]^T
        #pragma unroll
        for (int ks2 = 0; ks2 < 2; ++ks2){
            int col2 = (ks2 * 32 + lk * 8) * 2;
            bf16x8 a0 = *(const bf16x8*)(lds_h + ar0 * 128 + (col2 ^ swz));
            bf16x8 a1 = *(const bf16x8*)(lds_h + ar1 * 128 + (col2 ^ swz));
            const unsigned short* w2p = w2r + (size_t)(wv * 128 + l15) * D_FF + f0 + ks2 * 32 + lk * 8;
            #pragma unroll
            for (int nt = 0; nt < 8; ++nt){
                bf16x8 bb = *(const bf16x8*)(w2p + (size_t)nt * 16 * D_FF);
                yacc[0][nt] = __builtin_amdgcn_mfma_f32_16x16x32_bf16(a0, bb, yacc[0][nt], 0, 0, 0);
                yacc[1][nt] = __builtin_amdgcn_mfma_f32_16x16x32_bf16(a1, bb, yacc[1][nt], 0, 0, 0);
            }
        }
    }

    // ---- epilogue: out[tok] += p * Y   (exactly 2 atomic contributions per element -> deterministic)
    #pragma unroll
    for (int mt = 0; mt < 2; ++mt){
        #pragma unroll
        for (int r = 0; r < 4; ++r){
            int t = mt * 16 + lk * 4 + r;
            if (t < nrows){
                float p = s_prob[t];
                float* orow = out + (size_t)s_tok[t] * D_MODEL;
                #pragma unroll
                for (int nt = 0; nt < 8; ++nt){
                    int d = (wv * 8 + nt) * 16 + l15;
                    atomicAdd(orow + d, p * yacc[mt][nt][r]);
                }
            }
        }
    }
}

extern "C" void kernel_launch(void* const* d_in, const int* in_sizes, int n_in,
                              void* d_out, int out_size, void* d_ws, size_t ws_size,
                              hipStream_t stream){
    const float* x  = (const float*)d_in[0];
    const float* Wr = (const float*)d_in[1];
    const float* W1 = (const float*)d_in[2];
    const float* W2 = (const float*)d_in[3];
    float* out = (float*)d_out;

    char* ws = (char*)d_ws;
    unsigned short* x_bf  = (unsigned short*)(ws);                 //  8,388,608 B
    unsigned short* W1bf  = (unsigned short*)(ws + 8388608);       // 16,777,216 B
    unsigned short* W2bf  = (unsigned short*)(ws + 25165824);      // 16,777,216 B
    float* pair_prob      = (float*)(ws + 41943040);               //     65,536 B
    int*   lists          = (int*)(ws + 42008576);                 //    262,144 B
    int*   cnt            = (int*)(ws + 42270720);                 //         32 B

    hipMemsetAsync(cnt, 0, NE * sizeof(int), stream);
    hipMemsetAsync(d_out, 0, (size_t)out_size * sizeof(float), stream);

    cvt_f32_bf16<<<2048, 256, 0, stream>>>(x,  x_bf, (T_TOK * D_MODEL) / 4);
    cvt_f32_bf16<<<2048, 256, 0, stream>>>(W1, W1bf, (NE * D_FF * D_MODEL) / 4);
    cvt_f32_bf16<<<2048, 256, 0, stream>>>(W2, W2bf, (NE * D_MODEL * D_FF) / 4);

    router_kernel<<<(T_TOK * 64) / 256, 256, 0, stream>>>(x, Wr, pair_prob, lists, cnt);

    moe_ffn_kernel<<<520, 256, 0, stream>>>(x_bf, W1bf, W2bf, pair_prob, lists, cnt, out);
}